// Round 6
// baseline (112.480 us; speedup 1.0000x reference)
//
#include <hip/hip_runtime.h>

// NNSubmulti additive-attention block, MI355X (gfx950) — SINGLE KERNEL.
// B=16, TK=TQ=128, E=256, H=100.
// Block = (batch b, 8 key-rows i0..i0+7); grid = 256 blocks; 512 threads.
//   s1: stage W1[:, :E] bf16 -> LDS; a-GEMM (keys rows x W1a) -> a_s (x 2log2e)
//   s2: restage W1[:, E:]; c-GEMM (all 128 queries rows x W1b) -> cL (x 2log2e)
//       (c recomputed per block: 16x redundancy on a tiny MFMA op)
//   s3: sim[i,j] = sum_h w2[h]*tanh(a+c)  (tanh via exp2, args pre-scaled)
//   s4: softmax (1 wave per row), p *= key_mask via row scale
//   s5: keys_attn = p . queries; features mul/sub -> bf16 LDS
//   s6: out = relu(feat . Wlast^T + blast) via MFMA, Wlast f32->bf16 on the fly
// No workspace use at all; one dispatch (diagnoses harness fixed cost).

namespace {
constexpr int B  = 16;
constexpr int TQ = 128;
constexpr int TK = 128;
constexpr int E  = 256;
constexpr int H  = 100;
constexpr int HP = 112;        // padded H
constexpr int G  = 8;          // key-rows per block
constexpr int CLS = 116;       // cL row stride (floats): 116%32=20 -> ~8-way reads, 2-way writes
constexpr float SCALE = 2.8853900817779268f;  // 2*log2(e)
}

typedef __attribute__((ext_vector_type(8))) short short8;   // 8 bf16
typedef __attribute__((ext_vector_type(4))) float f32x4;

__device__ __forceinline__ unsigned short f2bf(float f) {
  unsigned u = __builtin_bit_cast(unsigned, f);
  u = (u + 0x7FFFu + ((u >> 16) & 1u)) >> 16;   // RTE
  return (unsigned short)u;
}
__device__ __forceinline__ unsigned pk2(float x, float y) {
  return (unsigned)f2bf(x) | ((unsigned)f2bf(y) << 16);
}
union U16 { uint4 u; short8 s; };
__device__ __forceinline__ short8 pack8(float4 a, float4 b) {
  U16 t;
  t.u = make_uint4(pk2(a.x, a.y), pk2(a.z, a.w), pk2(b.x, b.y), pk2(b.z, b.w));
  return t.s;
}

__global__ __launch_bounds__(512) void nns_fused(
    const float* __restrict__ queries, const float* __restrict__ keys,
    const float* __restrict__ qmask, const float* __restrict__ kmask,
    const float* __restrict__ W1, const float* __restrict__ b1,
    const float* __restrict__ W2, const float* __restrict__ Wlast,
    const float* __restrict__ blast, float* __restrict__ out) {
  union Region {                       // 59392 B = max member
    short ws[112 * 264];               // staged W1 half, bf16 (+8-short row pad)
    float cl[128 * CLS];               // c values, f32 (59392 B)
    struct {
      float simP[8 * 512];             // 16 KB
      float pL[8 * 128];               //  4 KB
      short featL[16 * 520];           // 16.6 KB (rows 8..15 zero)
    } p;
  };
  __shared__ Region R;
  __shared__ float a_s[G * HP];        // 3.6 KB, pre-scaled a rows
  __shared__ float w2s[HP];
  __shared__ float qm[TQ];
  // total static LDS ~ 63.9 KB -> 512 threads, 1-2 blocks/CU

  const int t    = threadIdx.x;
  const int blk  = blockIdx.x;         // 256 blocks
  const int b    = blk >> 4;
  const int i0   = (blk & 15) * G;
  const int wave = t >> 6, lane = t & 63;
  const int m    = lane & 15, kq = lane >> 4;

  // ---- s1a: stage W1[:, :E] -> ws (bf16, zero h>=100) ----
  #pragma unroll
  for (int i = 0; i < 7; ++i) {        // 3584 (h,seg) tasks
    const int idx = i * 512 + t;
    const int h = idx >> 5, seg = idx & 31;
    uint4 o = make_uint4(0u, 0u, 0u, 0u);
    if (h < H) {
      const float4* p4 = (const float4*)(W1 + (size_t)h * 512 + seg * 8);
      float4 u = p4[0], v = p4[1];
      o = make_uint4(pk2(u.x, u.y), pk2(u.z, u.w), pk2(v.x, v.y), pk2(v.z, v.w));
    }
    *(uint4*)(R.ws + h * 264 + seg * 8) = o;
  }
  if (t < HP) w2s[t] = (t < H) ? W2[t] : 0.0f;
  if (t < TQ) qm[t]  = qmask[b * TQ + t];
  __syncthreads();

  // ---- s1b: a-GEMM — waves 0..6 each one h-tile; A rows = keys i0..i0+15 ----
  if (wave < 7) {
    const int krow = b * TK + min(i0 + m, TK - 1);   // rows >= i0+8 unused
    f32x4 acc = {0.f, 0.f, 0.f, 0.f};
    #pragma unroll
    for (int kc = 0; kc < 8; ++kc) {
      const float4* kp = (const float4*)(keys + (size_t)krow * E + kc * 32 + kq * 8);
      short8 af = pack8(kp[0], kp[1]);
      short8 bf = *(const short8*)(R.ws + (wave * 16 + m) * 264 + kc * 32 + kq * 8);
      acc = __builtin_amdgcn_mfma_f32_16x16x32_bf16(af, bf, acc, 0, 0, 0);
    }
    const int h  = wave * 16 + m;                    // covers 0..111
    const float bias = (h < H) ? b1[h] : 0.0f;
    const int lr = (lane >> 4) * 4;                  // D rows 0,4,8,12
    if (lr < 8) {
      #pragma unroll
      for (int r = 0; r < 4; ++r)
        a_s[(lr + r) * HP + h] = (acc[r] + bias) * SCALE;
    }
  }
  __syncthreads();

  // ---- s2a: restage W1[:, E:] -> ws ----
  #pragma unroll
  for (int i = 0; i < 7; ++i) {
    const int idx = i * 512 + t;
    const int h = idx >> 5, seg = idx & 31;
    uint4 o = make_uint4(0u, 0u, 0u, 0u);
    if (h < H) {
      const float4* p4 = (const float4*)(W1 + (size_t)h * 512 + 256 + seg * 8);
      float4 u = p4[0], v = p4[1];
      o = make_uint4(pk2(u.x, u.y), pk2(u.z, u.w), pk2(v.x, v.y), pk2(v.z, v.w));
    }
    *(uint4*)(R.ws + h * 264 + seg * 8) = o;
  }
  __syncthreads();

  // ---- s2b: c-GEMM — wave = j-tile (16 rows), all 7 h-tiles ----
  {
    f32x4 accc[7];
    #pragma unroll
    for (int nt = 0; nt < 7; ++nt) accc[nt] = f32x4{0.f, 0.f, 0.f, 0.f};
    const int qrow = b * TQ + wave * 16 + m;
    #pragma unroll
    for (int kc = 0; kc < 8; ++kc) {
      const float4* qp = (const float4*)(queries + (size_t)qrow * E + kc * 32 + kq * 8);
      short8 af = pack8(qp[0], qp[1]);
      #pragma unroll
      for (int nt = 0; nt < 7; ++nt) {
        short8 bf = *(const short8*)(R.ws + (nt * 16 + m) * 264 + kc * 32 + kq * 8);
        accc[nt] = __builtin_amdgcn_mfma_f32_16x16x32_bf16(af, bf, accc[nt], 0, 0, 0);
      }
    }
    __syncthreads();                   // all ws reads done before overwrite
    const int jb = wave * 16 + (lane >> 4) * 4;
    #pragma unroll
    for (int nt = 0; nt < 7; ++nt) {
      const int h = nt * 16 + m;
      #pragma unroll
      for (int r = 0; r < 4; ++r)
        R.cl[(jb + r) * CLS + h] = accc[nt][r] * SCALE;   // 2-way write conflict
    }
  }
  __syncthreads();

  // ---- s3a: pull this thread's c-column + w2 into registers ----
  const int j = t & (TQ - 1);
  const int q = t >> 7;                // h-quarter 0..3
  float4 cr[7], wr[7];
  float wsum = 0.0f;
  {
    const float4* c4 = (const float4*)R.cl + j * (CLS / 4) + q * 7;
    const float4* w4 = (const float4*)w2s + q * 7;
    #pragma unroll
    for (int k = 0; k < 7; ++k) {
      cr[k] = c4[k];                   // one-time, ~8-way conflict
      wr[k] = w4[k];
      wsum += wr[k].x + wr[k].y + wr[k].z + wr[k].w;
    }
  }
  __syncthreads();                     // cl dead; region becomes simP/pL/featL

  // zero featL rows 8..15 (520 uint4)
  {
    uint4* z = (uint4*)(R.p.featL + 8 * 520);
    for (int i = t; i < 520; i += 512) z[i] = make_uint4(0u, 0u, 0u, 0u);
  }

  // ---- s3b: sim partials (tanh via exp2; args pre-scaled by 2log2e) ----
  {
    const float4* a4p = (const float4*)a_s + q * 7;
    #pragma unroll
    for (int g = 0; g < G; ++g) {
      float s = 0.0f;                  // s = sum_h w[h]*rcp(exp2(xs)+1)
      #pragma unroll
      for (int k = 0; k < 7; ++k) {
        float4 a4 = a4p[g * 28 + k];   // wave-uniform broadcast
        s = fmaf(wr[k].x, __builtin_amdgcn_rcpf(exp2f(a4.x + cr[k].x) + 1.0f), s);
        s = fmaf(wr[k].y, __builtin_amdgcn_rcpf(exp2f(a4.y + cr[k].y) + 1.0f), s);
        s = fmaf(wr[k].z, __builtin_amdgcn_rcpf(exp2f(a4.z + cr[k].z) + 1.0f), s);
        s = fmaf(wr[k].w, __builtin_amdgcn_rcpf(exp2f(a4.w + cr[k].w) + 1.0f), s);
      }
      R.p.simP[g * 512 + t] = wsum - 2.0f * s;
    }
  }
  __syncthreads();

  // ---- s4: softmax, one wave per row g ----
  {
    const float* sp = R.p.simP + wave * 512;
    float sv0 = sp[lane]      + sp[lane + 128] + sp[lane + 256] + sp[lane + 384];
    float sv1 = sp[lane + 64] + sp[lane + 192] + sp[lane + 320] + sp[lane + 448];
    if (qm[lane] == 0.0f)      sv0 = -4294967295.0f;
    if (qm[lane + 64] == 0.0f) sv1 = -4294967295.0f;
    float p0 = __expf(sv0), p1 = __expf(sv1);  // |sim| <= sum|W2| ~ 24: safe
    float s = p0 + p1;
    #pragma unroll
    for (int off = 1; off < 64; off <<= 1) s += __shfl_xor(s, off, 64);
    float inv = __builtin_amdgcn_rcpf(s);
    R.p.pL[wave * TQ + lane]      = p0 * inv;
    R.p.pL[wave * TQ + lane + 64] = p1 * inv;
  }
  __syncthreads();

  // ---- s5: keys_attn + features (each thread: one e, 4 g-rows) ----
  {
    const int e = t & 255, gh = t >> 8;
    float ka[4] = {0.f, 0.f, 0.f, 0.f};
    const float* qb = queries + (size_t)b * TQ * E + e;
    const float4* p4 = (const float4*)R.p.pL + (gh * 4) * 32;
    for (int j4 = 0; j4 < TQ / 4; ++j4) {
      float4 pv[4];
      #pragma unroll
      for (int gg = 0; gg < 4; ++gg) pv[gg] = p4[gg * 32 + j4];
      #pragma unroll
      for (int c = 0; c < 4; ++c) {
        float qv = qb[(size_t)(j4 * 4 + c) * E];   // coalesced
        #pragma unroll
        for (int gg = 0; gg < 4; ++gg)
          ka[gg] = fmaf(((const float*)&pv[gg])[c], qv, ka[gg]);
      }
    }
    #pragma unroll
    for (int gg = 0; gg < 4; ++gg) {
      const int g = gh * 4 + gg;
      const float kmv = kmask[b * TK + i0 + g];
      const float kav = ka[gg] * kmv;
      const float kv  = keys[((size_t)b * TK + i0 + g) * E + e];
      R.p.featL[g * 520 + e]     = (short)f2bf(kav * kv);   // feature_mul
      float d = kav - kv;
      R.p.featL[g * 520 + E + e] = (short)f2bf(d * d);      // feature_sub
    }
  }
  __syncthreads();

  // ---- s6: out = relu(feat . Wlast^T + blast); Wlast f32->bf16 on the fly ----
  {
    f32x4 acc[2] = {{0.f, 0.f, 0.f, 0.f}, {0.f, 0.f, 0.f, 0.f}};
    #pragma unroll
    for (int kc = 0; kc < 16; ++kc) {            // K=512, 32 per step
      short8 a = *(const short8*)(R.p.featL + m * 520 + kc * 32 + kq * 8);
      #pragma unroll
      for (int nt = 0; nt < 2; ++nt) {
        const int ncol = wave * 32 + nt * 16 + m;
        const float4* wp = (const float4*)(Wlast + (size_t)ncol * 512 + kc * 32 + kq * 8);
        short8 bfv = pack8(wp[0], wp[1]);
        acc[nt] = __builtin_amdgcn_mfma_f32_16x16x32_bf16(a, bfv, acc[nt], 0, 0, 0);
      }
    }
    const int rbase = (lane >> 4) * 4;           // valid D rows 0..7
    if (rbase < 8) {
      #pragma unroll
      for (int nt = 0; nt < 2; ++nt) {
        const int ncol = wave * 32 + nt * 16 + m;
        const float bl = blast[ncol];
        #pragma unroll
        for (int r = 0; r < 4; ++r)
          out[((size_t)b * TK + i0 + rbase + r) * E + ncol] =
              fmaxf(acc[nt][r] + bl, 0.0f);
      }
    }
  }
}

// ------------------------------------------------------------- launch ----
extern "C" void kernel_launch(void* const* d_in, const int* in_sizes, int n_in,
                              void* d_out, int out_size, void* d_ws, size_t ws_size,
                              hipStream_t stream) {
  (void)in_sizes; (void)n_in; (void)out_size; (void)d_ws; (void)ws_size;
  const float* queries = (const float*)d_in[0];
  const float* keys    = (const float*)d_in[1];
  const float* qmask   = (const float*)d_in[2];
  const float* kmask   = (const float*)d_in[3];
  const float* W1      = (const float*)d_in[4];
  const float* b1      = (const float*)d_in[5];
  const float* W2      = (const float*)d_in[6];
  const float* Wlast   = (const float*)d_in[7];
  const float* blast   = (const float*)d_in[8];
  float* out = (float*)d_out;

  nns_fused<<<dim3(B * (TK / G)), dim3(512), 0, stream>>>(
      queries, keys, qmask, kmask, W1, b1, W2, Wlast, blast, out);
}

// Round 8
// 107.660 us; speedup vs baseline: 1.0448x; 1.0448x over previous
//
#include <hip/hip_runtime.h>

// NNSubmulti additive-attention block, MI355X (gfx950).
// B=16, TK=TQ=128, E=256, H=100.
//
// K0 convert: keys||queries -> Xb bf16 [4096][256]; W1 -> Wb1 bf16 [112][512]
//             (zero-pad h>=100); Wlast -> Wb bf16 [256][512].
// K1 prep_gemm: a[b,i,h] = (b1[h] + keys_i . W1[h,:E]) * 2log2e  -> Aws
//               c[b,j,h] = (queries_j . W1[h,E:])      * 2log2e  -> Cws
//               Per-wave 16x16 MFMA tiles, operands straight from L2.
//               NO LDS, NO barriers (occupancy-first).
//               NOTE: koff selects the W1 half (R7 bug: it was missing).
// K2 attn: per block = (batch b, 4 key-rows). 512 blocks x 256 thr.
//          sim (tanh via exp2, pre-scaled args) -> per-wave softmax ->
//          p.queries -> features bf16 (LDS, 4 valid rows of 16; MFMA D-rows
//          depend only on the matching A-row, so rows 4..15 stay garbage) ->
//          relu(feat.Wlast^T + blast) via MFMA with Wb from L2 -> d_out.

namespace {
constexpr int B  = 16;
constexpr int TQ = 128;
constexpr int TK = 128;
constexpr int E  = 256;
constexpr int H  = 100;
constexpr int HP = 112;
constexpr int G  = 4;                        // key-rows per attn block
constexpr float SCALE = 2.8853900817779268f; // 2*log2(e)
}

typedef __attribute__((ext_vector_type(8))) short short8;   // 8 bf16
typedef __attribute__((ext_vector_type(4))) float f32x4;

__device__ __forceinline__ unsigned short f2bf(float f) {
  unsigned u = __builtin_bit_cast(unsigned, f);
  u = (u + 0x7FFFu + ((u >> 16) & 1u)) >> 16;   // RTE
  return (unsigned short)u;
}
__device__ __forceinline__ unsigned pk2(float x, float y) {
  return (unsigned)f2bf(x) | ((unsigned)f2bf(y) << 16);
}
__device__ __forceinline__ uint4 pack8u(float4 a, float4 b) {
  return make_uint4(pk2(a.x, a.y), pk2(a.z, a.w), pk2(b.x, b.y), pk2(b.z, b.w));
}

// ---------------------------------------------------------------- K0 ----
__global__ __launch_bounds__(256) void convert_bf16(
    const float* __restrict__ queries, const float* __restrict__ keys,
    const float* __restrict__ W1, const float* __restrict__ Wlast,
    unsigned short* __restrict__ Xb, unsigned short* __restrict__ Wb1,
    unsigned short* __restrict__ Wb) {
  const int blk = blockIdx.x, t = threadIdx.x;
  if (blk < 512) {                        // Xb: 4096x256 (keys rows 0..2047)
    const int idx = blk * 2048 + t * 8;
    const int row = idx >> 8, e = idx & 255;
    const float* src = (row < B * TK) ? keys + (size_t)row * E + e
                                      : queries + (size_t)(row - B * TK) * E + e;
    const float4* p4 = (const float4*)src;
    *(uint4*)(Xb + idx) = pack8u(p4[0], p4[1]);
  } else if (blk < 540) {                 // Wb1: 112x512, zero h>=100
    const int idx = (blk - 512) * 2048 + t * 8;
    const int h = idx >> 9;
    uint4 o = make_uint4(0u, 0u, 0u, 0u);
    if (h < H) {
      const float4* p4 = (const float4*)(W1 + idx);
      o = pack8u(p4[0], p4[1]);
    }
    *(uint4*)(Wb1 + idx) = o;
  } else {                                // Wb: 256x512
    const int idx = (blk - 540) * 2048 + t * 8;
    const float4* p4 = (const float4*)(Wlast + idx);
    *(uint4*)(Wb + idx) = pack8u(p4[0], p4[1]);
  }
}

// ---------------------------------------------------------------- K1 ----
// 1792 wave-tasks = 256 m-tiles x 7 n-tiles; 448 blocks x 4 waves.
__global__ __launch_bounds__(256, 4) void prep_gemm(
    const unsigned short* __restrict__ Xb, const unsigned short* __restrict__ Wb1,
    const float* __restrict__ b1, float* __restrict__ A, float* __restrict__ C) {
  const int t = threadIdx.x;
  const int tid = blockIdx.x * 4 + (t >> 6);   // wave task
  const int mt = tid / 7, nt = tid % 7;
  const int lane = t & 63, m = lane & 15, kq = lane >> 4;

  const bool isA = (mt * 16 < B * TK);         // tile never straddles 2048
  const int koff = isA ? 0 : 256;              // W1[:, :E] vs W1[:, E:]  (R7 fix)

  const unsigned short* ap = Xb + (size_t)(mt * 16 + m) * 256 + kq * 8;
  const unsigned short* bp = Wb1 + (size_t)(nt * 16 + m) * 512 + koff + kq * 8;
  f32x4 acc = {0.f, 0.f, 0.f, 0.f};
  #pragma unroll
  for (int kc = 0; kc < 8; ++kc) {
    short8 af = *(const short8*)(ap + kc * 32);
    short8 bf = *(const short8*)(bp + kc * 32);
    acc = __builtin_amdgcn_mfma_f32_16x16x32_bf16(af, bf, acc, 0, 0, 0);
  }
  // D: col = lane&15 -> h; row = (lane>>4)*4 + r -> X-row
  const int h = nt * 16 + m;
  const float bias = (isA && h < H) ? b1[h] : 0.0f;
  float* dst = isA ? (A + (size_t)(mt * 16) * HP)
                   : (C + (size_t)(mt * 16 - B * TK) * HP);
  const int rbase = (lane >> 4) * 4;
  #pragma unroll
  for (int r = 0; r < 4; ++r)
    dst[(size_t)(rbase + r) * HP + h] = (acc[r] + bias) * SCALE;
}

// ---------------------------------------------------------------- K2 ----
__global__ __launch_bounds__(256, 4) void attn(
    const float* __restrict__ queries, const float* __restrict__ keys,
    const float* __restrict__ qmask, const float* __restrict__ kmask,
    const float* __restrict__ W2, const float* __restrict__ blast,
    const float* __restrict__ A, const float* __restrict__ C,
    const unsigned short* __restrict__ Wb, float* __restrict__ out) {
  __shared__ float a_s[G * HP];        // 1.8 KB, pre-scaled a rows
  __shared__ float w2s[HP];
  __shared__ float qm[TQ];
  __shared__ float simP[G * 256];      // 4 KB
  __shared__ float pL[G * TQ];         // 2 KB
  __shared__ short featL[16 * 520];    // 16.6 KB; only rows 0..3 written

  const int t    = threadIdx.x;
  const int blk  = blockIdx.x;         // 512 blocks
  const int b    = blk >> 5;
  const int i0   = (blk & 31) * G;
  const int wave = t >> 6, lane = t & 63;
  const int m    = lane & 15, kq = lane >> 4;

  // ---- stage ----
  if (t < G * HP / 4)
    ((float4*)a_s)[t] = ((const float4*)(A + ((size_t)b * TK + i0) * HP))[t];
  if (t < HP) w2s[t] = (t < H) ? W2[t] : 0.0f;
  if (t < TQ) qm[t]  = qmask[b * TQ + t];
  __syncthreads();

  // ---- sim: thread = (j, h-half); 2 quarter-passes; c from L2 ----
  {
    const int j  = t & 127;
    const int h2 = t >> 7;                       // 0: quarters 0,1; 1: 2,3
    float acc[G] = {0.f, 0.f, 0.f, 0.f};
    #pragma unroll
    for (int pp = 0; pp < 2; ++pp) {
      const int q = h2 * 2 + pp;
      float4 cr[7], wr[7];
      float wsum = 0.0f;
      const float4* c4 = (const float4*)(C + ((size_t)b * TQ + j) * HP + q * 28);
      const float4* w4 = (const float4*)w2s + q * 7;
      #pragma unroll
      for (int k = 0; k < 7; ++k) {
        cr[k] = c4[k];
        wr[k] = w4[k];
        wsum += wr[k].x + wr[k].y + wr[k].z + wr[k].w;
      }
      const float4* a4p = (const float4*)a_s + q * 7;
      #pragma unroll
      for (int g = 0; g < G; ++g) {
        float s = 0.0f;                          // sum_h w*rcp(exp2(xs)+1)
        #pragma unroll
        for (int k = 0; k < 7; ++k) {
          float4 a4 = a4p[g * 28 + k];           // wave-uniform broadcast
          s = fmaf(wr[k].x, __builtin_amdgcn_rcpf(exp2f(a4.x + cr[k].x) + 1.0f), s);
          s = fmaf(wr[k].y, __builtin_amdgcn_rcpf(exp2f(a4.y + cr[k].y) + 1.0f), s);
          s = fmaf(wr[k].z, __builtin_amdgcn_rcpf(exp2f(a4.z + cr[k].z) + 1.0f), s);
          s = fmaf(wr[k].w, __builtin_amdgcn_rcpf(exp2f(a4.w + cr[k].w) + 1.0f), s);
        }
        acc[g] += wsum - 2.0f * s;               // sum_h w*tanh over quarter
      }
    }
    #pragma unroll
    for (int g = 0; g < G; ++g) simP[g * 256 + t] = acc[g];
  }
  __syncthreads();

  // ---- softmax: wave g owns row g ----
  {
    const float* sp = simP + wave * 256;
    float sv0 = sp[lane]      + sp[lane + 128];
    float sv1 = sp[lane + 64] + sp[lane + 192];
    if (qm[lane] == 0.0f)      sv0 = -4294967295.0f;   // -2^32+1
    if (qm[lane + 64] == 0.0f) sv1 = -4294967295.0f;
    float p0 = __expf(sv0), p1 = __expf(sv1);   // |sim| <= sum|W2| ~24: safe
    float s = p0 + p1;
    #pragma unroll
    for (int off = 1; off < 64; off <<= 1) s += __shfl_xor(s, off, 64);
    float inv = __builtin_amdgcn_rcpf(s);
    pL[wave * TQ + lane]      = p0 * inv;
    pL[wave * TQ + lane + 64] = p1 * inv;
  }
  __syncthreads();

  // ---- keys_attn + features: thread = one e, all 4 g-rows ----
  {
    const int e = t;
    float ka[G] = {0.f, 0.f, 0.f, 0.f};
    const float* qb = queries + (size_t)b * TQ * E + e;
    const float4* p4 = (const float4*)pL;
    for (int j4 = 0; j4 < TQ / 4; ++j4) {
      float4 pv[G];
      #pragma unroll
      for (int g = 0; g < G; ++g) pv[g] = p4[g * 32 + j4];   // broadcast
      #pragma unroll
      for (int c = 0; c < 4; ++c) {
        float qv = qb[(size_t)(j4 * 4 + c) * E];             // coalesced
        #pragma unroll
        for (int g = 0; g < G; ++g)
          ka[g] = fmaf(((const float*)&pv[g])[c], qv, ka[g]);
      }
    }
    #pragma unroll
    for (int g = 0; g < G; ++g) {
      const float kmv = kmask[b * TK + i0 + g];
      const float kav = ka[g] * kmv;
      const float kv  = keys[((size_t)b * TK + i0 + g) * E + e];
      featL[g * 520 + e]     = (short)f2bf(kav * kv);        // feature_mul
      float d = kav - kv;
      featL[g * 520 + E + e] = (short)f2bf(d * d);           // feature_sub
    }
  }
  __syncthreads();

  // ---- out = relu(feat . Wlast^T + blast): wave = 64 N-cols, Wb from L2 ----
  {
    f32x4 acc[4];
    #pragma unroll
    for (int nt = 0; nt < 4; ++nt) acc[nt] = f32x4{0.f, 0.f, 0.f, 0.f};
    #pragma unroll
    for (int kc = 0; kc < 16; ++kc) {            // K=512
      short8 a = *(const short8*)(featL + m * 520 + kc * 32 + kq * 8);
      #pragma unroll
      for (int nt = 0; nt < 4; ++nt) {
        const int ncol = wave * 64 + nt * 16 + m;
        short8 bf = *(const short8*)(Wb + (size_t)ncol * 512 + kc * 32 + kq * 8);
        acc[nt] = __builtin_amdgcn_mfma_f32_16x16x32_bf16(a, bf, acc[nt], 0, 0, 0);
      }
    }
    if ((lane >> 4) == 0) {                      // D rows 0..3 = the 4 g-rows
      #pragma unroll
      for (int nt = 0; nt < 4; ++nt) {
        const int ncol = wave * 64 + nt * 16 + m;
        const float bl = blast[ncol];
        #pragma unroll
        for (int r = 0; r < 4; ++r)
          out[((size_t)b * TK + i0 + r) * E + ncol] = fmaxf(acc[nt][r] + bl, 0.0f);
      }
    }
  }
}

// ------------------------------------------------------------- launch ----
extern "C" void kernel_launch(void* const* d_in, const int* in_sizes, int n_in,
                              void* d_out, int out_size, void* d_ws, size_t ws_size,
                              hipStream_t stream) {
  (void)in_sizes; (void)n_in; (void)out_size; (void)ws_size;
  const float* queries = (const float*)d_in[0];
  const float* keys    = (const float*)d_in[1];
  const float* qmask   = (const float*)d_in[2];
  const float* kmask   = (const float*)d_in[3];
  const float* W1      = (const float*)d_in[4];
  const float* b1      = (const float*)d_in[5];
  const float* W2      = (const float*)d_in[6];
  const float* Wlast   = (const float*)d_in[7];
  const float* blast   = (const float*)d_in[8];
  float* out = (float*)d_out;

  float* A = (float*)d_ws;                                  // [2048][112] f32
  float* C = A + (size_t)B * TK * HP;                       // [2048][112] f32
  unsigned short* Wb1 = (unsigned short*)(C + (size_t)B * TQ * HP); // [112][512]
  unsigned short* Wb  = Wb1 + (size_t)HP * 512;             // [256][512]
  unsigned short* Xb  = Wb + (size_t)E * 512;               // [4096][256]
  // ws usage ~4.3 MiB

  convert_bf16<<<dim3(604), dim3(256), 0, stream>>>(
      queries, keys, W1, Wlast, Xb, Wb1, Wb);
  prep_gemm<<<dim3(448), dim3(256), 0, stream>>>(Xb, Wb1, b1, A, C);
  attn<<<dim3(512), dim3(256), 0, stream>>>(
      queries, keys, qmask, kmask, W2, blast, A, C, Wb, out);
}